// Round 2
// baseline (131.834 us; speedup 1.0000x reference)
//
#include <hip/hip_runtime.h>
#include <stdint.h>

#define I_DIM 2048
#define O_DIM 8192
#define T_TOK 512
#define NSTR  64
#define TT    64
#define BK    64
#define NSTEP (I_DIM / BK)

// GEMM LDS layout (48KB path)
#define A_HI 0
#define A_LO 8192
#define B_HI 16384
#define B_LO 32768
#define SMEM_BYTES 49152

// Fallback (round-1) LDS layout
#define FB_MU_OFF 49152
#define FB_THR_OFF 57344
#define FB_SMEM_BYTES 65536

#define TILE_B 16384  // bytes per (stripe,step) per component (128 o x 64 k x bf16)

typedef __attribute__((ext_vector_type(8))) short bf16x8;
typedef __attribute__((ext_vector_type(4))) float f32x4;
typedef __attribute__((ext_vector_type(4))) int i32x4;

__device__ __forceinline__ unsigned short f2bf_rne(float f) {
  unsigned u = __builtin_bit_cast(unsigned, f);
  u += 0x7fffu + ((u >> 16) & 1u);
  return (unsigned short)(u >> 16);
}
__device__ __forceinline__ float bf2f(unsigned short h) {
  return __builtin_bit_cast(float, ((unsigned)h) << 16);
}
__device__ __forceinline__ unsigned short f2bf_trunc(float f) {
  return (unsigned short)(__builtin_bit_cast(unsigned, f) >> 16);
}
__device__ __forceinline__ void gload16(const void* g, void* l) {
  __builtin_amdgcn_global_load_lds(
      (const __attribute__((address_space(1))) void*)g,
      (__attribute__((address_space(3))) void*)l, 16, 0, 0);
}

// k0: thrs[n][i] = thresholds[n][i] * std[i]; zero per-token mask counters.
__global__ void cwic_init(const float* __restrict__ thresholds,
                          const float* __restrict__ stdv,
                          float* __restrict__ thrs, int* __restrict__ counts) {
  int idx = blockIdx.x * 256 + threadIdx.x;  // covers 64*2048 exactly
  thrs[idx] = thresholds[idx] * stdv[idx & (I_DIM - 1)];
  if (idx < T_TOK) counts[idx] = 0;
}

// k0b: one-shot weight split f32 -> bf16 hi/lo, written pre-swizzled in the exact
// per-(stripe,step) LDS tile image the GEMM will global_load_lds (m173 pattern).
__global__ __launch_bounds__(256) void cwic_wprep(const float* __restrict__ w,
                                                  char* __restrict__ whi,
                                                  char* __restrict__ wlo) {
  const int bp = blockIdx.x;  // 2048 = 64 stripes x 32 steps
  const int n = bp >> 5, step = bp & 31;
  const int tid = threadIdx.x;
  const int o = tid & 127, kh = tid >> 7;
  const float* wp = w + (size_t)(step * BK + kh * 32) * O_DIM + n * 128 + o;
  const size_t tile = (size_t)bp * TILE_B;
  char* hb = whi + tile;
  char* lb = wlo + tile;
  const int rowb = o * 128;
  const int swz = (o & 7) << 4;
  #pragma unroll
  for (int g = 0; g < 4; ++g) {
    i32x4 hv, lv;
    unsigned hprev = 0, lprev = 0;
    #pragma unroll
    for (int e = 0; e < 8; ++e) {
      float v = wp[(size_t)(g * 8 + e) * O_DIM];
      unsigned short h = f2bf_rne(v);
      unsigned short lo = f2bf_trunc(v - bf2f(h));
      if ((e & 1) == 0) { hprev = h; lprev = lo; }
      else {
        hv[e >> 1] = (int)(hprev | ((unsigned)h << 16));
        lv[e >> 1] = (int)(lprev | ((unsigned)lo << 16));
      }
    }
    *(i32x4*)(hb + rowb + ((kh * 64 + g * 16) ^ swz)) = hv;
    *(i32x4*)(lb + rowb + ((kh * 64 + g * 16) ^ swz)) = lv;
  }
}

// k1: per-stripe masked GEMM, B staged via global_load_lds from pre-split tiles.
// A[t,i] = (|x-mu| > thr) ? x : mu  (== xc*mask + mu, folds post_mu for free).
__global__ __launch_bounds__(256, 3) void cwic_gemm2(
    const float* __restrict__ x, const char* __restrict__ whi,
    const char* __restrict__ wlo, const float* __restrict__ bias,
    const float* __restrict__ thrs, const float* __restrict__ mu,
    float* __restrict__ y, int* __restrict__ counts) {
  extern __shared__ char smem[];
  const int b = blockIdx.x;
  // XCD swizzle: 8 token-tiles of one stripe land on one XCD -> B tiles L2-hot.
  const int nid = (b & 7) * 64 + (b >> 3);
  const int n = nid >> 3;
  const int tt = nid & 7;
  const int trow0 = tt * TT;
  const int ocol0 = n * 128;
  const int tid = threadIdx.x;

  f32x4 acc[2][4];
  #pragma unroll
  for (int mi = 0; mi < 2; ++mi)
    #pragma unroll
    for (int ni = 0; ni < 4; ++ni)
      acc[mi][ni] = (f32x4)(0.0f);

  const int t_loc = tid >> 2, kq = tid & 3;     // A staging: token row, k-quarter
  const int lane = tid & 63, wid = tid >> 6;
  const int wr = wid >> 1, wc = wid & 1;
  const int l15 = lane & 15, l4 = lane >> 4;
  const float* thr_row = thrs + (size_t)n * I_DIM;
  const char* htiles = whi + (size_t)(n * 32) * TILE_B;
  const char* ltiles = wlo + (size_t)(n * 32) * TILE_B;
  int cnt = 0;

  for (int step = 0; step < NSTEP; ++step) {
    const int kk0 = step * BK;
    // ---- stage B: 8 x global_load_lds(16B) from pre-swizzled tiles ----
    {
      const char* hs = htiles + (size_t)step * TILE_B + tid * 16;
      const char* ls = ltiles + (size_t)step * TILE_B + tid * 16;
      #pragma unroll
      for (int j = 0; j < 4; ++j) {
        gload16(hs + j * 4096, smem + B_HI + j * 4096 + tid * 16);
        gload16(ls + j * 4096, smem + B_LO + j * 4096 + tid * 16);
      }
    }
    // ---- stage A: mask + hi/lo split of 64 tokens x 64 k ----
    {
      const float* xp = x + (size_t)(trow0 + t_loc) * I_DIM + kk0 + kq * 16;
      const float* mup = mu + kk0 + kq * 16;
      const float* thp = thr_row + kk0 + kq * 16;
      const int rowb = t_loc * 128;
      const int swz = (t_loc & 7) << 4;
      #pragma unroll
      for (int g = 0; g < 2; ++g) {
        float4 x0 = *(const float4*)(xp + g * 8);
        float4 x1 = *(const float4*)(xp + g * 8 + 4);
        float4 m0 = *(const float4*)(mup + g * 8);
        float4 m1 = *(const float4*)(mup + g * 8 + 4);
        float4 t0 = *(const float4*)(thp + g * 8);
        float4 t1 = *(const float4*)(thp + g * 8 + 4);
        float xs[8] = {x0.x, x0.y, x0.z, x0.w, x1.x, x1.y, x1.z, x1.w};
        float ms[8] = {m0.x, m0.y, m0.z, m0.w, m1.x, m1.y, m1.z, m1.w};
        float ts[8] = {t0.x, t0.y, t0.z, t0.w, t1.x, t1.y, t1.z, t1.w};
        i32x4 hv, lv;
        unsigned hprev = 0, lprev = 0;
        #pragma unroll
        for (int e = 0; e < 8; ++e) {
          float xc = xs[e] - ms[e];
          bool keep = fabsf(xc) > ts[e];
          cnt += keep ? 1 : 0;
          float a = keep ? xs[e] : ms[e];  // xc*mask + mu
          unsigned short h = f2bf_rne(a);
          unsigned short lo = f2bf_trunc(a - bf2f(h));
          if ((e & 1) == 0) { hprev = h; lprev = lo; }
          else {
            hv[e >> 1] = (int)(hprev | ((unsigned)h << 16));
            lv[e >> 1] = (int)(lprev | ((unsigned)lo << 16));
          }
        }
        *(i32x4*)(smem + A_HI + rowb + (((kq * 32) + g * 16) ^ swz)) = hv;
        *(i32x4*)(smem + A_LO + rowb + (((kq * 32) + g * 16) ^ swz)) = lv;
      }
    }
    __syncthreads();
    // ---- compute: 2 K32 substeps, 24 ds_read_b128 + 48 MFMA per step ----
    #pragma unroll
    for (int s32 = 0; s32 < 2; ++s32) {
      bf16x8 afh[2], afl[2];
      #pragma unroll
      for (int mi = 0; mi < 2; ++mi) {
        const int r = wr * 32 + mi * 16 + l15;
        const int ad = r * 128 + (((s32 * 64) + l4 * 16) ^ ((r & 7) << 4));
        afh[mi] = *(const bf16x8*)(smem + A_HI + ad);
        afl[mi] = *(const bf16x8*)(smem + A_LO + ad);
      }
      #pragma unroll
      for (int ni = 0; ni < 4; ++ni) {
        const int o = wc * 64 + ni * 16 + l15;
        const int ad = o * 128 + (((s32 * 64) + l4 * 16) ^ ((o & 7) << 4));
        bf16x8 bh = *(const bf16x8*)(smem + B_HI + ad);
        bf16x8 bl = *(const bf16x8*)(smem + B_LO + ad);
        #pragma unroll
        for (int mi = 0; mi < 2; ++mi) {
          acc[mi][ni] = __builtin_amdgcn_mfma_f32_16x16x32_bf16(afh[mi], bh, acc[mi][ni], 0, 0, 0);
          acc[mi][ni] = __builtin_amdgcn_mfma_f32_16x16x32_bf16(afh[mi], bl, acc[mi][ni], 0, 0, 0);
          acc[mi][ni] = __builtin_amdgcn_mfma_f32_16x16x32_bf16(afl[mi], bh, acc[mi][ni], 0, 0, 0);
        }
      }
    }
    __syncthreads();
  }

  cnt += __shfl_xor(cnt, 1);
  cnt += __shfl_xor(cnt, 2);
  if ((tid & 3) == 0) atomicAdd(&counts[trow0 + t_loc], cnt);

  #pragma unroll
  for (int ni = 0; ni < 4; ++ni) {
    const int o = ocol0 + wc * 64 + ni * 16 + l15;
    const float bv = bias[o];
    #pragma unroll
    for (int mi = 0; mi < 2; ++mi) {
      const int row0 = trow0 + wr * 32 + mi * 16 + l4 * 4;
      #pragma unroll
      for (int r = 0; r < 4; ++r) {
        y[(size_t)(row0 + r) * O_DIM + o] = acc[mi][ni][r] + bv;
      }
    }
  }
}

// Fallback (round-1 kernel, verified passing): used only if ws too small.
__global__ __launch_bounds__(256, 2) void cwic_gemm_fb(
    const float* __restrict__ x, const float* __restrict__ w,
    const float* __restrict__ bias, const float* __restrict__ thrs,
    const float* __restrict__ mu, float* __restrict__ y,
    int* __restrict__ counts) {
  extern __shared__ char smem[];
  const int b = blockIdx.x;
  const int nid = (b & 7) * 64 + (b >> 3);
  const int n = nid >> 3;
  const int tt = nid & 7;
  const int trow0 = tt * TT;
  const int ocol0 = n * 128;
  const int tid = threadIdx.x;

  float* mu_s = (float*)(smem + FB_MU_OFF);
  float* thr_s = (float*)(smem + FB_THR_OFF);
  {
    const float4* mu4 = (const float4*)mu;
    const float4* th4 = (const float4*)(thrs + (size_t)n * I_DIM);
    #pragma unroll
    for (int i = 0; i < 2; ++i) {
      int idx = tid + i * 256;
      ((float4*)mu_s)[idx] = mu4[idx];
      ((float4*)thr_s)[idx] = th4[idx];
    }
  }
  __syncthreads();

  f32x4 acc[2][4];
  #pragma unroll
  for (int mi = 0; mi < 2; ++mi)
    #pragma unroll
    for (int ni = 0; ni < 4; ++ni)
      acc[mi][ni] = (f32x4)(0.0f);

  const int t_loc = tid >> 2, kq = tid & 3;
  const int o_loc = tid & 127, kh = tid >> 7;
  const int lane = tid & 63, wid = tid >> 6;
  const int wr = wid >> 1, wc = wid & 1;
  const int l15 = lane & 15, l4 = lane >> 4;
  int cnt = 0;

  for (int step = 0; step < NSTEP; ++step) {
    const int kk0 = step * BK;
    {
      const float* xp = x + (size_t)(trow0 + t_loc) * I_DIM + kk0 + kq * 16;
      const float* mup = mu_s + kk0 + kq * 16;
      const float* thp = thr_s + kk0 + kq * 16;
      const int rowb = t_loc * 128;
      const int swz = (t_loc & 7) << 4;
      #pragma unroll
      for (int g = 0; g < 2; ++g) {
        float4 x0 = *(const float4*)(xp + g * 8);
        float4 x1 = *(const float4*)(xp + g * 8 + 4);
        float4 m0 = *(const float4*)(mup + g * 8);
        float4 m1 = *(const float4*)(mup + g * 8 + 4);
        float4 t0 = *(const float4*)(thp + g * 8);
        float4 t1 = *(const float4*)(thp + g * 8 + 4);
        float xs[8] = {x0.x, x0.y, x0.z, x0.w, x1.x, x1.y, x1.z, x1.w};
        float ms[8] = {m0.x, m0.y, m0.z, m0.w, m1.x, m1.y, m1.z, m1.w};
        float ts[8] = {t0.x, t0.y, t0.z, t0.w, t1.x, t1.y, t1.z, t1.w};
        i32x4 hv, lv;
        unsigned hprev = 0, lprev = 0;
        #pragma unroll
        for (int e = 0; e < 8; ++e) {
          float xc = xs[e] - ms[e];
          bool keep = fabsf(xc) > ts[e];
          cnt += keep ? 1 : 0;
          float a = keep ? xs[e] : ms[e];
          unsigned short h = f2bf_rne(a);
          unsigned short lo = f2bf_trunc(a - bf2f(h));
          if ((e & 1) == 0) { hprev = h; lprev = lo; }
          else {
            hv[e >> 1] = (int)(hprev | ((unsigned)h << 16));
            lv[e >> 1] = (int)(lprev | ((unsigned)lo << 16));
          }
        }
        *(i32x4*)(smem + A_HI + rowb + (((kq * 32) + g * 16) ^ swz)) = hv;
        *(i32x4*)(smem + A_LO + rowb + (((kq * 32) + g * 16) ^ swz)) = lv;
      }
    }
    {
      const float* wp = w + (size_t)(kk0 + kh * 32) * O_DIM + ocol0 + o_loc;
      const int rowb = o_loc * 128;
      const int swz = (o_loc & 7) << 4;
      #pragma unroll
      for (int g = 0; g < 4; ++g) {
        i32x4 hv, lv;
        unsigned hprev = 0, lprev = 0;
        #pragma unroll
        for (int e = 0; e < 8; ++e) {
          float v = wp[(size_t)(g * 8 + e) * O_DIM];
          unsigned short h = f2bf_rne(v);
          unsigned short lo = f2bf_trunc(v - bf2f(h));
          if ((e & 1) == 0) { hprev = h; lprev = lo; }
          else {
            hv[e >> 1] = (int)(hprev | ((unsigned)h << 16));
            lv[e >> 1] = (int)(lprev | ((unsigned)lo << 16));
          }
        }
        *(i32x4*)(smem + B_HI + rowb + (((kh * 64) + g * 16) ^ swz)) = hv;
        *(i32x4*)(smem + B_LO + rowb + (((kh * 64) + g * 16) ^ swz)) = lv;
      }
    }
    __syncthreads();
    #pragma unroll
    for (int s32 = 0; s32 < 2; ++s32) {
      bf16x8 afh[2], afl[2];
      #pragma unroll
      for (int mi = 0; mi < 2; ++mi) {
        const int r = wr * 32 + mi * 16 + l15;
        const int ad = r * 128 + (((s32 * 64) + l4 * 16) ^ ((r & 7) << 4));
        afh[mi] = *(const bf16x8*)(smem + A_HI + ad);
        afl[mi] = *(const bf16x8*)(smem + A_LO + ad);
      }
      #pragma unroll
      for (int ni = 0; ni < 4; ++ni) {
        const int o = wc * 64 + ni * 16 + l15;
        const int ad = o * 128 + (((s32 * 64) + l4 * 16) ^ ((o & 7) << 4));
        bf16x8 bh = *(const bf16x8*)(smem + B_HI + ad);
        bf16x8 bl = *(const bf16x8*)(smem + B_LO + ad);
        #pragma unroll
        for (int mi = 0; mi < 2; ++mi) {
          acc[mi][ni] = __builtin_amdgcn_mfma_f32_16x16x32_bf16(afh[mi], bh, acc[mi][ni], 0, 0, 0);
          acc[mi][ni] = __builtin_amdgcn_mfma_f32_16x16x32_bf16(afh[mi], bl, acc[mi][ni], 0, 0, 0);
          acc[mi][ni] = __builtin_amdgcn_mfma_f32_16x16x32_bf16(afl[mi], bh, acc[mi][ni], 0, 0, 0);
        }
      }
    }
    __syncthreads();
  }

  cnt += __shfl_xor(cnt, 1);
  cnt += __shfl_xor(cnt, 2);
  if ((tid & 3) == 0) atomicAdd(&counts[trow0 + t_loc], cnt);

  #pragma unroll
  for (int ni = 0; ni < 4; ++ni) {
    const int o = ocol0 + wc * 64 + ni * 16 + l15;
    const float bv = bias[o];
    #pragma unroll
    for (int mi = 0; mi < 2; ++mi) {
      const int row0 = trow0 + wr * 32 + mi * 16 + l4 * 4;
      #pragma unroll
      for (int r = 0; r < 4; ++r) {
        y[(size_t)(row0 + r) * O_DIM + o] = acc[mi][ni][r] + bv;
      }
    }
  }
}

// k2: flops outputs. flops_sparse = 16777216 * count/(64*2048) = 128*count (exact).
__global__ void cwic_fin(const int* __restrict__ counts, float* __restrict__ outF) {
  int t = blockIdx.x * 256 + threadIdx.x;
  outF[t] = 16777216.0f;
  outF[T_TOK + t] = 128.0f * (float)counts[t];
}

extern "C" void kernel_launch(void* const* d_in, const int* in_sizes, int n_in,
                              void* d_out, int out_size, void* d_ws, size_t ws_size,
                              hipStream_t stream) {
  const float* x = (const float*)d_in[0];
  const float* w = (const float*)d_in[1];
  const float* bias = (const float*)d_in[2];
  const float* thresholds = (const float*)d_in[3];
  const float* mu = (const float*)d_in[4];
  const float* stdv = (const float*)d_in[5];
  float* y = (float*)d_out;

  char* ws = (char*)d_ws;
  float* thrs = (float*)ws;                                   // 64*2048 f32 = 512KB
  int* counts = (int*)(ws + (size_t)NSTR * I_DIM * 4);        // 512 i32
  const size_t WHI_OFF = (size_t)1 << 20;
  const size_t WCOMP = (size_t)NSTR * NSTEP * TILE_B;         // 32MB per component
  const size_t WLO_OFF = WHI_OFF + WCOMP;
  const size_t NEED = WLO_OFF + WCOMP;

  cwic_init<<<(NSTR * I_DIM) / 256, 256, 0, stream>>>(thresholds, stdv, thrs, counts);
  if (ws_size >= NEED) {
    char* whi = ws + WHI_OFF;
    char* wlo = ws + WLO_OFF;
    cwic_wprep<<<NSTR * NSTEP, 256, 0, stream>>>(w, whi, wlo);
    cwic_gemm2<<<512, 256, SMEM_BYTES, stream>>>(x, whi, wlo, bias, thrs, mu, y, counts);
  } else {
    cwic_gemm_fb<<<512, 256, FB_SMEM_BYTES, stream>>>(x, w, bias, thrs, mu, y, counts);
  }
  cwic_fin<<<2, 256, 0, stream>>>(counts, y + (size_t)T_TOK * O_DIM);
}

// Round 3
// 108.439 us; speedup vs baseline: 1.2157x; 1.2157x over previous
//
#include <hip/hip_runtime.h>
#include <stdint.h>

#define I_DIM 2048
#define O_DIM 8192
#define T_TOK 512
#define NSTR  64
#define TT    64
#define BK    64
#define NSTEP (I_DIM / BK)

// GEMM LDS layout (64KB)
#define A_HI 0
#define A_LO 8192
#define B_HI 16384
#define B_LO 32768
#define MU_OFF 49152
#define THR_OFF 57344
#define SMEM_BYTES 65536

#define TILE_B 16384  // bytes per (stripe,step) per component (128 o x 64 k x bf16)

typedef __attribute__((ext_vector_type(8))) short bf16x8;
typedef __attribute__((ext_vector_type(4))) float f32x4;
typedef __attribute__((ext_vector_type(4))) int i32x4;

__device__ __forceinline__ unsigned short f2bf_rne(float f) {
  unsigned u = __builtin_bit_cast(unsigned, f);
  u += 0x7fffu + ((u >> 16) & 1u);
  return (unsigned short)(u >> 16);
}
__device__ __forceinline__ float bf2f(unsigned short h) {
  return __builtin_bit_cast(float, ((unsigned)h) << 16);
}
__device__ __forceinline__ unsigned short f2bf_trunc(float f) {
  return (unsigned short)(__builtin_bit_cast(unsigned, f) >> 16);
}
__device__ __forceinline__ void gload16(const void* g, void* l) {
  __builtin_amdgcn_global_load_lds(
      (const __attribute__((address_space(1))) void*)g,
      (__attribute__((address_space(3))) void*)l, 16, 0, 0);
}

// k0: zero per-token mask counters (512 ints).
__global__ void cwic_zero(int* __restrict__ counts) {
  counts[blockIdx.x * 256 + threadIdx.x] = 0;
}

// k0b: one-shot weight split f32 -> bf16 hi/lo, written pre-swizzled in the exact
// per-(stripe,step) LDS tile image the GEMM will global_load_lds (m173 pattern).
__global__ __launch_bounds__(256) void cwic_wprep(const float* __restrict__ w,
                                                  char* __restrict__ whi,
                                                  char* __restrict__ wlo) {
  const int bp = blockIdx.x;  // 2048 = 64 stripes x 32 steps
  const int n = bp >> 5, step = bp & 31;
  const int tid = threadIdx.x;
  const int o = tid & 127, kh = tid >> 7;
  const float* wp = w + (size_t)(step * BK + kh * 32) * O_DIM + n * 128 + o;
  const size_t tile = (size_t)bp * TILE_B;
  char* hb = whi + tile;
  char* lb = wlo + tile;
  const int rowb = o * 128;
  const int swz = (o & 7) << 4;
  #pragma unroll
  for (int g = 0; g < 4; ++g) {
    i32x4 hv, lv;
    unsigned hprev = 0, lprev = 0;
    #pragma unroll
    for (int e = 0; e < 8; ++e) {
      float v = wp[(size_t)(g * 8 + e) * O_DIM];
      unsigned short h = f2bf_rne(v);
      unsigned short lo = f2bf_trunc(v - bf2f(h));
      if ((e & 1) == 0) { hprev = h; lprev = lo; }
      else {
        hv[e >> 1] = (int)(hprev | ((unsigned)h << 16));
        lv[e >> 1] = (int)(lprev | ((unsigned)lo << 16));
      }
    }
    *(i32x4*)(hb + rowb + ((kh * 64 + g * 16) ^ swz)) = hv;
    *(i32x4*)(lb + rowb + ((kh * 64 + g * 16) ^ swz)) = lv;
  }
}

// k1: per-stripe masked GEMM. B staged via global_load_lds from pre-split tiles;
// x register-prefetched one step ahead; mu/thr LDS-resident (staged in prologue).
// A[t,i] = (|x-mu| > thr) ? x : mu  (== xc*mask + mu, folds post_mu for free).
__global__ __launch_bounds__(256, 2) void cwic_gemm3(
    const float* __restrict__ x, const char* __restrict__ whi,
    const char* __restrict__ wlo, const float* __restrict__ bias,
    const float* __restrict__ thresholds, const float* __restrict__ stdv,
    const float* __restrict__ mu, float* __restrict__ y,
    int* __restrict__ counts) {
  extern __shared__ char smem[];
  const int b = blockIdx.x;
  // XCD swizzle: 8 token-tiles of one stripe land on one XCD -> B tiles L2-hot.
  const int nid = (b & 7) * 64 + (b >> 3);
  const int n = nid >> 3;
  const int tt = nid & 7;
  const int trow0 = tt * TT;
  const int ocol0 = n * 128;
  const int tid = threadIdx.x;

  // ---- prologue: stage mu and thr(=thresholds*std) into LDS ----
  float* mu_s = (float*)(smem + MU_OFF);
  float* thr_s = (float*)(smem + THR_OFF);
  {
    const float4* mu4 = (const float4*)mu;
    const float4* th4 = (const float4*)(thresholds + (size_t)n * I_DIM);
    const float4* sd4 = (const float4*)stdv;
    #pragma unroll
    for (int i = 0; i < 2; ++i) {
      int idx = tid + i * 256;
      float4 m = mu4[idx];
      float4 t = th4[idx];
      float4 s = sd4[idx];
      float4 ts;
      ts.x = t.x * s.x; ts.y = t.y * s.y; ts.z = t.z * s.z; ts.w = t.w * s.w;
      ((float4*)mu_s)[idx] = m;
      ((float4*)thr_s)[idx] = ts;
    }
  }

  f32x4 acc[2][4];
  #pragma unroll
  for (int mi = 0; mi < 2; ++mi)
    #pragma unroll
    for (int ni = 0; ni < 4; ++ni)
      acc[mi][ni] = (f32x4)(0.0f);

  const int t_loc = tid >> 2, kq = tid & 3;     // A staging: token row, k-quarter
  const int lane = tid & 63, wid = tid >> 6;
  const int wr = wid >> 1, wc = wid & 1;
  const int l15 = lane & 15, l4 = lane >> 4;
  const char* htiles = whi + (size_t)(n * 32) * TILE_B;
  const char* ltiles = wlo + (size_t)(n * 32) * TILE_B;
  const float* xrow = x + (size_t)(trow0 + t_loc) * I_DIM + kq * 16;
  int cnt = 0;

  // prefetch x for step 0
  float4 xr[2][4];
  #pragma unroll
  for (int j = 0; j < 4; ++j) xr[0][j] = *(const float4*)(xrow + j * 4);

  __syncthreads();  // mu/thr ready

  for (int sp = 0; sp < NSTEP; sp += 2) {
    #pragma unroll
    for (int s2 = 0; s2 < 2; ++s2) {
      const int step = sp + s2;
      const int kk0 = step * BK;
      // (1) prefetch x for step+1 (clamped on last step; values then unused)
      {
        const int kk1 = (step + 1 < NSTEP) ? (kk0 + BK) : kk0;
        #pragma unroll
        for (int j = 0; j < 4; ++j)
          xr[s2 ^ 1][j] = *(const float4*)(xrow + kk1 + j * 4);
      }
      // (2) stage B: 8 x global_load_lds(16B) from pre-swizzled tiles
      {
        const char* hs = htiles + (size_t)step * TILE_B + tid * 16;
        const char* ls = ltiles + (size_t)step * TILE_B + tid * 16;
        #pragma unroll
        for (int j = 0; j < 4; ++j) {
          gload16(hs + j * 4096, smem + B_HI + j * 4096 + tid * 16);
          gload16(ls + j * 4096, smem + B_LO + j * 4096 + tid * 16);
        }
      }
      // (3) stage A from prefetched regs; mu/thr from LDS
      {
        const int rowb = t_loc * 128;
        const int swz = (t_loc & 7) << 4;
        #pragma unroll
        for (int g = 0; g < 2; ++g) {
          float4 x0 = xr[s2][g * 2];
          float4 x1 = xr[s2][g * 2 + 1];
          float4 m0 = *(const float4*)(mu_s + kk0 + kq * 16 + g * 8);
          float4 m1 = *(const float4*)(mu_s + kk0 + kq * 16 + g * 8 + 4);
          float4 t0 = *(const float4*)(thr_s + kk0 + kq * 16 + g * 8);
          float4 t1 = *(const float4*)(thr_s + kk0 + kq * 16 + g * 8 + 4);
          float xs[8] = {x0.x, x0.y, x0.z, x0.w, x1.x, x1.y, x1.z, x1.w};
          float ms[8] = {m0.x, m0.y, m0.z, m0.w, m1.x, m1.y, m1.z, m1.w};
          float ts[8] = {t0.x, t0.y, t0.z, t0.w, t1.x, t1.y, t1.z, t1.w};
          i32x4 hv, lv;
          unsigned hprev = 0, lprev = 0;
          #pragma unroll
          for (int e = 0; e < 8; ++e) {
            float xc = xs[e] - ms[e];
            bool keep = fabsf(xc) > ts[e];
            cnt += keep ? 1 : 0;
            float a = keep ? xs[e] : ms[e];  // xc*mask + mu
            unsigned short h = f2bf_rne(a);
            unsigned short lo = f2bf_trunc(a - bf2f(h));
            if ((e & 1) == 0) { hprev = h; lprev = lo; }
            else {
              hv[e >> 1] = (int)(hprev | ((unsigned)h << 16));
              lv[e >> 1] = (int)(lprev | ((unsigned)lo << 16));
            }
          }
          *(i32x4*)(smem + A_HI + rowb + (((kq * 32) + g * 16) ^ swz)) = hv;
          *(i32x4*)(smem + A_LO + rowb + (((kq * 32) + g * 16) ^ swz)) = lv;
        }
      }
      __syncthreads();
      // (4) compute: 2 K32 substeps, 24 ds_read_b128 + 48 MFMA per step
      __builtin_amdgcn_s_setprio(1);
      #pragma unroll
      for (int s32 = 0; s32 < 2; ++s32) {
        bf16x8 afh[2], afl[2];
        #pragma unroll
        for (int mi = 0; mi < 2; ++mi) {
          const int r = wr * 32 + mi * 16 + l15;
          const int ad = r * 128 + (((s32 * 64) + l4 * 16) ^ ((r & 7) << 4));
          afh[mi] = *(const bf16x8*)(smem + A_HI + ad);
          afl[mi] = *(const bf16x8*)(smem + A_LO + ad);
        }
        #pragma unroll
        for (int ni = 0; ni < 4; ++ni) {
          const int o = wc * 64 + ni * 16 + l15;
          const int ad = o * 128 + (((s32 * 64) + l4 * 16) ^ ((o & 7) << 4));
          bf16x8 bh = *(const bf16x8*)(smem + B_HI + ad);
          bf16x8 bl = *(const bf16x8*)(smem + B_LO + ad);
          #pragma unroll
          for (int mi = 0; mi < 2; ++mi) {
            acc[mi][ni] = __builtin_amdgcn_mfma_f32_16x16x32_bf16(afh[mi], bh, acc[mi][ni], 0, 0, 0);
            acc[mi][ni] = __builtin_amdgcn_mfma_f32_16x16x32_bf16(afh[mi], bl, acc[mi][ni], 0, 0, 0);
            acc[mi][ni] = __builtin_amdgcn_mfma_f32_16x16x32_bf16(afl[mi], bh, acc[mi][ni], 0, 0, 0);
          }
        }
      }
      __builtin_amdgcn_s_setprio(0);
      __syncthreads();
    }
  }

  // ---- mask-count reduce: 4 threads (kq) share one token ----
  cnt += __shfl_xor(cnt, 1);
  cnt += __shfl_xor(cnt, 2);
  if ((tid & 3) == 0) atomicAdd(&counts[trow0 + t_loc], cnt);

  // ---- epilogue: C/D layout col=lane&15, row=(lane>>4)*4+reg (m89-verified) ----
  #pragma unroll
  for (int ni = 0; ni < 4; ++ni) {
    const int o = ocol0 + wc * 64 + ni * 16 + l15;
    const float bv = bias[o];
    #pragma unroll
    for (int mi = 0; mi < 2; ++mi) {
      const int row0 = trow0 + wr * 32 + mi * 16 + l4 * 4;
      #pragma unroll
      for (int r = 0; r < 4; ++r) {
        y[(size_t)(row0 + r) * O_DIM + o] = acc[mi][ni][r] + bv;
      }
    }
  }
}

// k2: flops outputs. flops_sparse = 16777216 * count/(64*2048) = 128*count (exact).
__global__ void cwic_fin(const int* __restrict__ counts, float* __restrict__ outF) {
  int t = blockIdx.x * 256 + threadIdx.x;
  outF[t] = 16777216.0f;
  outF[T_TOK + t] = 128.0f * (float)counts[t];
}

extern "C" void kernel_launch(void* const* d_in, const int* in_sizes, int n_in,
                              void* d_out, int out_size, void* d_ws, size_t ws_size,
                              hipStream_t stream) {
  const float* x = (const float*)d_in[0];
  const float* w = (const float*)d_in[1];
  const float* bias = (const float*)d_in[2];
  const float* thresholds = (const float*)d_in[3];
  const float* mu = (const float*)d_in[4];
  const float* stdv = (const float*)d_in[5];
  float* y = (float*)d_out;

  char* ws = (char*)d_ws;
  const size_t WCOMP = (size_t)NSTR * NSTEP * TILE_B;  // 32MB per component
  char* whi = ws;
  char* wlo = ws + WCOMP;
  int* counts = (int*)(ws + 2 * WCOMP);  // 512 i32

  cwic_zero<<<2, 256, 0, stream>>>(counts);
  cwic_wprep<<<NSTR * NSTEP, 256, 0, stream>>>(w, whi, wlo);
  cwic_gemm3<<<512, 256, SMEM_BYTES, stream>>>(x, whi, wlo, bias, thresholds,
                                               stdv, mu, y, counts);
  cwic_fin<<<2, 256, 0, stream>>>(counts, y + (size_t)T_TOK * O_DIM);
}